// Round 6
// baseline (1346.584 us; speedup 1.0000x reference)
//
#include <hip/hip_runtime.h>
#include <cstddef>
#include <cstdint>

// ---------------------------------------------------------------------------
// LSTM layer: T=512, B=64, I=512, H=512.
// Phase 1: xW = x @ W + b  (bf16 MFMA GEMM), epilogue writes xWp in
//          per-WG-per-step contiguous layout [t][blk8][slice16][gate][256].
// Phase 2: persistent recurrence, 128 WGs = 8 batch-blocks x 16 hidden-slices.
//   R13: XCD-local exchange (i_blk = blockIdx & 7 residue class -> one XCD
//        under round-robin dispatch). Dual-publish (workgroup-scope -> local
//        L2 copy, then agent-scope -> MALL). sc0 poll loads with sticky sc1
//        escape hatch. Verified: FETCH dropped 337->116 MB (reads L2-hit).
//   R14: deferred out-store. vmcnt is FIFO, so step t+1's poll waitcnt was
//        draining step t's out-store HBM ack (~700-900cy) before the poll
//        loads could complete — invariant across R8..R13 and the reason no
//        read-path change moved the period. Fix: hold the out element in
//        registers and issue its nt store only after the NEXT step's poll
//        succeeds, so the ack overlaps that step's compute. Flush after loop.
// ---------------------------------------------------------------------------

#define T_STEPS 512
#define NB      64      // batch
#define HID     512
#define G4      2048    // 4*H
#define KDIM    512
#define BB      8       // batch blocks (8 rows each)
#define NSL     16      // hidden slices (32 units each)
#define BLK_DW  (NSL * 256)          // dwords per (parity,block) region = 4096
#define PAR_DW  (BB * BLK_DW)        // dwords per parity = 32768

typedef short bf16x8 __attribute__((ext_vector_type(8)));
typedef float f32x4  __attribute__((ext_vector_type(4)));
typedef unsigned int u32x4 __attribute__((ext_vector_type(4)));

__device__ __forceinline__ float bf2f(unsigned short s) {
    unsigned u = ((unsigned)s) << 16;
    float f; __builtin_memcpy(&f, &u, 4); return f;
}
__device__ __forceinline__ unsigned short f2bf(float f) {
    unsigned u; __builtin_memcpy(&u, &f, 4);
    u = (u + 0x7FFFu + ((u >> 16) & 1u)) >> 16;
    return (unsigned short)u;
}
__device__ __forceinline__ unsigned min4(u32x4 v) {
    unsigned a = v[0] < v[1] ? v[0] : v[1];
    unsigned b = v[2] < v[3] ? v[2] : v[3];
    return a < b ? a : b;
}

// ---------------- kernel 1: cast x to bf16 + zero both abq parity regions --
__global__ void cast_x_kernel(const float* __restrict__ x,
                              unsigned short* __restrict__ o,
                              unsigned* __restrict__ abq) {
    if (blockIdx.x < 256)   // 256 x 256 = 65536 dwords = 256 KB
        abq[blockIdx.x * 256 + threadIdx.x] = 0u;   // tag 0 = stale
    size_t i = (size_t)blockIdx.x * blockDim.x + threadIdx.x;  // one float4 each
    float4 v = ((const float4*)x)[i];
    ushort4 r;
    r.x = f2bf(v.x); r.y = f2bf(v.y); r.z = f2bf(v.z); r.w = f2bf(v.w);
    ((ushort4*)o)[i] = r;
}

// ---------------- kernel 2: transpose+cast [512][2048] f32 -> [2048][512] bf16
__global__ void transpose_cast(const float* __restrict__ src,
                               unsigned short* __restrict__ dst) {
    __shared__ float tile[64][65];
    const int n0 = blockIdx.x * 64;
    const int k0 = blockIdx.y * 64;
    const int c  = threadIdx.x & 63;
    const int r0 = threadIdx.x >> 6;
    for (int p = 0; p < 16; ++p) {
        int r = p * 4 + r0;
        tile[r][c] = src[(size_t)(k0 + r) * G4 + n0 + c];
    }
    __syncthreads();
    for (int p = 0; p < 16; ++p) {
        int r = p * 4 + r0;
        dst[(size_t)(n0 + r) * KDIM + k0 + c] = f2bf(tile[c][r]);
    }
}

// ---------------- kernel 3: bf16 MFMA GEMM, recurrence-layout epilogue ------
// C layout: [t][blk8][slice16][gate][bt*32+ut] bf16 (2 KB per WG-step)
__global__ __launch_bounds__(256) void gemm_xw(
        const unsigned short* __restrict__ A,
        const unsigned short* __restrict__ Bt,
        const float* __restrict__ bias,
        unsigned short* __restrict__ C) {
    __shared__ unsigned short As[128][56];
    __shared__ unsigned short Bs[128][56];
    const int m0 = blockIdx.x * 128;
    const int n0 = blockIdx.y * 128;
    const int tid = threadIdx.x;
    const int lane = tid & 63, wave = tid >> 6;
    const int quad = lane >> 4, l16 = lane & 15;
    const int wm = (wave >> 1) * 64, wn = (wave & 1) * 64;
    f32x4 acc[4][4];
    for (int i = 0; i < 4; ++i)
        for (int j = 0; j < 4; ++j) acc[i][j] = (f32x4)0.0f;
    const int srow = tid >> 2, scol = (tid & 3) * 8;
    for (int k0 = 0; k0 < KDIM; k0 += 32) {
        __syncthreads();
        for (int p = 0; p < 2; ++p) {
            int row = p * 64 + srow;
            *(uint4*)&As[row][scol] =
                *(const uint4*)&A[(size_t)(m0 + row) * KDIM + k0 + scol];
            *(uint4*)&Bs[row][scol] =
                *(const uint4*)&Bt[(size_t)(n0 + row) * KDIM + k0 + scol];
        }
        __syncthreads();
        bf16x8 af[4], bf[4];
        for (int i = 0; i < 4; ++i)
            af[i] = *(const bf16x8*)&As[wm + i * 16 + l16][quad * 8];
        for (int j = 0; j < 4; ++j)
            bf[j] = *(const bf16x8*)&Bs[wn + j * 16 + l16][quad * 8];
        for (int i = 0; i < 4; ++i)
            for (int j = 0; j < 4; ++j)
                acc[i][j] = __builtin_amdgcn_mfma_f32_16x16x32_bf16(
                    af[i], bf[j], acc[i][j], 0, 0, 0);
    }
    for (int i = 0; i < 4; ++i)
        for (int j = 0; j < 4; ++j) {
            int col = n0 + wn + j * 16 + l16;          // 0..2047
            int g   = col >> 9;                        // gate
            int u   = col & 511;                       // hidden unit
            int js  = u >> 5, utl = u & 31;            // slice, unit-local
            float bv = bias[col];
            for (int r = 0; r < 4; ++r) {
                int row = m0 + wm + i * 16 + quad * 4 + r;   // t*64 + b
                int t = row >> 6, b = row & 63;
                size_t off = ((((size_t)t * BB + (b >> 3)) * NSL + js) * 4 + g)
                                 * 256 + (b & 7) * 32 + utl;
                C[off] = f2bf(acc[i][j][r] + bv);
            }
        }
}

// ---------------- kernel 4: persistent recurrence (XCD-local exchange) -----
// abq dword layout: [parity][block i8][slice j16][d], d = b_local*32 + u_local.
// Word = bf16(value) | version<<16. Version of a_t is t+1 (a0 -> 1).
__global__ __launch_bounds__(256, 1) void lstm_rec(
        const unsigned short* __restrict__ xWp,  // [t][blk][slice][4][256] bf16
        const unsigned short* __restrict__ Ut,   // [2048][512] bf16
        const float* __restrict__ a0,            // [64][512] f32
        float* __restrict__ out,                 // [T*64][512] f32
        unsigned* __restrict__ abq) {            // 2*PAR_DW dwords = 256 KB
    __shared__ unsigned short a_lds[16][520];    // [batch-local][k-global]
    __shared__ float gbuf[4][8][36];             // [gate][batch-local][unit]
    const int wgid  = blockIdx.x;
    const int i_blk = wgid & 7;                  // batch block 0..7 = XCD id
    const int j_sl  = wgid >> 3;                 // hidden slice 0..15
    const int tid   = threadIdx.x;
    const int wave  = tid >> 6;                  // gate index
    const int lane  = tid & 63;
    const int quad  = lane >> 4, l16 = lane & 15;
    const int j0 = j_sl * 32;
    const int b0 = i_blk * 8;
    const int bt = tid >> 5;                     // batch-local  0..7
    const int ut = tid & 31;                     // unit-local   0..31

    // zero MFMA A rows 8..15 once (M=16 tile, only 8 batch rows valid)
    for (int i = tid; i < 2080; i += 256)
        ((unsigned*)&a_lds[8][0])[i] = 0u;

    // --- register-resident B fragments: gate `wave`, 32 units (2 N-tiles) ---
    bf16x8 bq[2][16];
#pragma unroll
    for (int n = 0; n < 2; ++n) {
        const unsigned short* urow =
            Ut + (size_t)(wave * HID + j0 + n * 16 + l16) * KDIM + quad * 8;
#pragma unroll
        for (int s = 0; s < 16; ++s)
            bq[n][s] = *(const bf16x8*)(urow + s * 32);
    }

    // --- per-thread state + init dual-publish (version 1 -> parity 0) ---
    float aown = a0[(size_t)(b0 + bt) * HID + j0 + ut];
    {
        unsigned* pp = &abq[(size_t)i_blk * BLK_DW + j_sl * 256 + tid];
        unsigned pv = (unsigned)f2bf(aown) | (1u << 16);
        __hip_atomic_store(pp, pv, __ATOMIC_RELAXED, __HIP_MEMORY_SCOPE_WORKGROUP);
        __hip_atomic_store(pp, pv, __ATOMIC_RELAXED, __HIP_MEMORY_SCOPE_AGENT);
    }

    // --- xW addend prefetch pipeline (A/B register buffers) ---
    unsigned short xsA[4], xsB[4];
    {
        const unsigned short* xp =
            xWp + ((size_t)i_blk * NSL + j_sl) * 1024;   // t = 0
#pragma unroll
        for (int w = 0; w < 4; ++w)
            xsA[w] = xp[w * 256 + tid];
    }

    bool fast = true;    // sticky: sc0 (L2) loads until starvation detected
    // deferred out-store state (R14): issued after NEXT step's poll succeeds
    float    pend_a   = 0.0f;
    unsigned pend_idx = 0xFFFFFFFFu;

#define LOADS(FLAG)                                                         \
    asm volatile(                                                           \
        "global_load_dwordx4 %0, %4, off " FLAG "\n\t"                      \
        "global_load_dwordx4 %1, %5, off " FLAG "\n\t"                      \
        "global_load_dwordx4 %2, %6, off " FLAG "\n\t"                      \
        "global_load_dwordx4 %3, %7, off " FLAG "\n\t"                      \
        "s_waitcnt vmcnt(0)"                                                \
        : "=&v"(d0), "=&v"(d1), "=&v"(d2), "=&v"(d3)                        \
        : "v"(pc), "v"(pc + 256), "v"(pc + 512), "v"(pc + 768)              \
        : "memory")

    auto step = [&](int t, unsigned short* xs, unsigned short* xsn) {
        // --- stage a_{t-1}: 4 tagged 16B chunks; bulk load doubles as poll.
        //     fast: sc0 (bypass L1, hit shared XCD L2). slow: sc1 (MALL). ---
        const unsigned* srcblk =
            abq + (size_t)(t & 1) * PAR_DW + (size_t)i_blk * BLK_DW;
        const u32x4* pc = (const u32x4*)srcblk + tid;
        const unsigned w16 = (unsigned)(t + 1) << 16;
        u32x4 d0, d1, d2, d3;
        bool okf;
        int tries = 0;
        do {
            if (__builtin_expect(fast, 1)) { LOADS("sc0"); }
            else                           { LOADS("sc1"); }
            unsigned m01 = min4(d0) < min4(d1) ? min4(d0) : min4(d1);
            unsigned m23 = min4(d2) < min4(d3) ? min4(d2) : min4(d3);
            okf = ((m01 < m23 ? m01 : m23) >= w16);
            if (!okf && ++tries > 32) fast = false;   // starving on stale L2
        } while (!okf);

        // --- R14: issue the PREVIOUS step's out-store now; its HBM ack
        //     overlaps this step's compute + next poll instead of being
        //     drained (FIFO vmcnt) at the head of this poll. nt: streaming. ---
        if (pend_idx != 0xFFFFFFFFu)
            __builtin_nontemporal_store(pend_a, &out[pend_idx]);

        // --- prefetch next step's xW addends (hidden under rest of step) ---
        {
            int tn = (t + 1 < T_STEPS) ? t + 1 : t;
            const unsigned short* xp =
                xWp + (((size_t)tn * BB + i_blk) * NSL + j_sl) * 1024;
#pragma unroll
            for (int w = 0; w < 4; ++w)
                xsn[w] = xp[w * 256 + tid];
        }

        // scatter to LDS: strip tags, 8B packed writes
        // dword d = j*256 + b*32 + u  ->  a_lds[b][j*32 + u]
#define SCAT(q, d)                                                          \
        {                                                                   \
            int dd = ((q) << 10) + tid * 4;                                 \
            int bb = (dd >> 5) & 7;                                         \
            int kg = ((dd >> 8) << 5) | (dd & 31);                          \
            unsigned lo = ((d)[0] & 0xffffu) | ((d)[1] << 16);              \
            unsigned hi = ((d)[2] & 0xffffu) | ((d)[3] << 16);              \
            uint2 pk; pk.x = lo; pk.y = hi;                                 \
            *(uint2*)&a_lds[bb][kg] = pk;                                   \
        }
        SCAT(0, d0) SCAT(1, d1) SCAT(2, d2) SCAT(3, d3)
#undef SCAT
        __syncthreads();

        // --- MFMA: M=16 (8 batch rows valid), N=32 (2 tiles), K=512 ---
        f32x4 acc0a = (f32x4)0.0f, acc0b = (f32x4)0.0f;
        f32x4 acc1a = (f32x4)0.0f, acc1b = (f32x4)0.0f;
#pragma unroll
        for (int s = 0; s < 16; s += 2) {
            bf16x8 af0 = *(const bf16x8*)&a_lds[l16][(s + 0) * 32 + quad * 8];
            bf16x8 af1 = *(const bf16x8*)&a_lds[l16][(s + 1) * 32 + quad * 8];
            acc0a = __builtin_amdgcn_mfma_f32_16x16x32_bf16(af0, bq[0][s + 0], acc0a, 0, 0, 0);
            acc1a = __builtin_amdgcn_mfma_f32_16x16x32_bf16(af0, bq[1][s + 0], acc1a, 0, 0, 0);
            acc0b = __builtin_amdgcn_mfma_f32_16x16x32_bf16(af1, bq[0][s + 1], acc0b, 0, 0, 0);
            acc1b = __builtin_amdgcn_mfma_f32_16x16x32_bf16(af1, bq[1][s + 1], acc1b, 0, 0, 0);
        }
        if (quad < 2) {
#pragma unroll
            for (int r = 0; r < 4; ++r) {
                gbuf[wave][quad * 4 + r][l16]      = acc0a[r] + acc0b[r];
                gbuf[wave][quad * 4 + r][16 + l16] = acc1a[r] + acc1b[r];
            }
        }
        __syncthreads();

        // --- gates (thread (bt,ut)); dual-publish FIRST, out deferred ---
        {
            float gu = gbuf[0][bt][ut] + bf2f(xs[0]);
            float gf = gbuf[1][bt][ut] + bf2f(xs[1]);
            float go = gbuf[2][bt][ut] + bf2f(xs[2]);
            float gc = gbuf[3][bt][ut] + bf2f(xs[3]);
            float su = 1.f / (1.f + __expf(-gu));
            float sf = 1.f / (1.f + __expf(-gf));
            float so = 1.f / (1.f + __expf(-go));
            float e2 = __expf(2.f * gc);
            float tc = 1.f - 2.f / (e2 + 1.f);            // tanh(gc)
            float cc = su * tc + sf * aown;                // forget * a_{t-1}
            float ec = __expf(2.f * cc);
            float th = 1.f - 2.f / (ec + 1.f);             // tanh(c)
            float a  = so * th;
            aown = a;
            unsigned* pp = &abq[(size_t)((t + 1) & 1) * PAR_DW +
                                (size_t)i_blk * BLK_DW + j_sl * 256 + tid];
            unsigned pv = (unsigned)f2bf(a) | ((unsigned)(t + 2) << 16);
            // workgroup-scope first (shared-L2 copy), agent-scope last
            __hip_atomic_store(pp, pv, __ATOMIC_RELAXED, __HIP_MEMORY_SCOPE_WORKGROUP);
            __hip_atomic_store(pp, pv, __ATOMIC_RELAXED, __HIP_MEMORY_SCOPE_AGENT);
            // defer the out-store (R14)
            pend_a   = a;
            pend_idx = (unsigned)((t * NB + b0 + bt) * HID + j0 + ut);
        }
        // the gbuf-phase __syncthreads separates a_lds reuse across steps
    };

    for (int t = 0; t < T_STEPS; t += 2) {
        step(t,     xsA, xsB);
        step(t + 1, xsB, xsA);
    }
    // flush last step's deferred out-store
    if (pend_idx != 0xFFFFFFFFu)
        __builtin_nontemporal_store(pend_a, &out[pend_idx]);
#undef LOADS
}

// ---------------------------------------------------------------------------
extern "C" void kernel_launch(void* const* d_in, const int* in_sizes, int n_in,
                              void* d_out, int out_size, void* d_ws, size_t ws_size,
                              hipStream_t stream) {
    (void)in_sizes; (void)n_in; (void)out_size; (void)ws_size;
    const float* x    = (const float*)d_in[0];   // [T,B,I]
    const float* a0   = (const float*)d_in[1];   // [B,H]
    const float* W    = (const float*)d_in[2];   // [I,4H]
    const float* U    = (const float*)d_in[3];   // [H,4H]
    const float* bias = (const float*)d_in[4];   // [4H]
    float* out = (float*)d_out;

    char* ws = (char*)d_ws;
    unsigned short* xbf  = (unsigned short*)(ws);                 // 33,554,432 B
    unsigned short* Wt   = (unsigned short*)(ws + 33554432);      //  2,097,152 B
    unsigned short* Ut   = (unsigned short*)(ws + 35651584);      //  2,097,152 B
    unsigned short* xWp  = (unsigned short*)(ws + 37748736);      // 134,217,728 B
    unsigned*       abq  = (unsigned*)(ws + 171966464);           //    262,144 B

    cast_x_kernel<<<16384, 256, 0, stream>>>(x, xbf, abq);
    transpose_cast<<<dim3(32, 8), 256, 0, stream>>>(W, Wt);
    transpose_cast<<<dim3(32, 8), 256, 0, stream>>>(U, Ut);
    gemm_xw<<<dim3(256, 16), 256, 0, stream>>>(xbf, Wt, bias, xWp);
    lstm_rec<<<BB * NSL, 256, 0, stream>>>(xWp, Ut, a0, out, abq);
}